// Round 21
// baseline (215.995 us; speedup 1.0000x reference)
//
#include <hip/hip_runtime.h>
#include <math.h>

#define TT 2048
#define DD 1024
#define HH 16
#define DKK 64
#define BB 4
#define NN 8192  // BB*TT

typedef __bf16 bf16x8 __attribute__((ext_vector_type(8)));
typedef float f32x4 __attribute__((ext_vector_type(4)));
typedef float f32x16 __attribute__((ext_vector_type(16)));
typedef unsigned int uint2v __attribute__((ext_vector_type(2)));

#define QSCALE 0.18033688011112043f   // 0.125 * log2(e)

// round-to-nearest-even f32 -> bf16 bits
__device__ __forceinline__ unsigned short f2bf(float f) {
  unsigned int u = __builtin_bit_cast(unsigned int, f);
  u += 0x7fffu + ((u >> 16) & 1u);
  return (unsigned short)(u >> 16);
}

// v_cvt_pk_bf16_f32: dst.lo16 = bf16(lo), dst.hi16 = bf16(hi)
__device__ __forceinline__ unsigned int cvtpk(float lo, float hi) {
  unsigned int r;
  asm("v_cvt_pk_bf16_f32 %0, %1, %2" : "=v"(r) : "v"(lo), "v"(hi));
  return r;
}

__device__ __forceinline__ void gl_lds16(const void* g, void* s) {
  __builtin_amdgcn_global_load_lds(
      (const __attribute__((address_space(1))) void*)g,
      (__attribute__((address_space(3))) void*)s, 16, 0, 0);
}

// XOR swizzle within a 128B row (both-sides pattern, verified rounds 2-20)
#define SWZ(r, byte) ((byte) ^ (((r) & 7) << 4))

// ---------------------------------------------------------------------------
// transpose + cast 4 weights (DDxDD f32 row-major [k][n]) -> WT bf16 [n][k]
__global__ __launch_bounds__(256) void wtrans(
    const float* __restrict__ W0, const float* __restrict__ W1,
    const float* __restrict__ W2, const float* __restrict__ W3,
    unsigned short* __restrict__ WT) {
  __shared__ float t[32][33];
  const float* W = (blockIdx.z == 0) ? W0
                   : (blockIdx.z == 1) ? W1
                   : (blockIdx.z == 2) ? W2 : W3;
  unsigned short* O = WT + (size_t)blockIdx.z * DD * DD;
  const int tx = threadIdx.x & 31, ty = threadIdx.x >> 5;
  const int r0 = blockIdx.y * 32, c0 = blockIdx.x * 32;
#pragma unroll
  for (int j = 0; j < 4; ++j)
    t[ty + 8 * j][tx] = W[(size_t)(r0 + ty + 8 * j) * DD + c0 + tx];
  __syncthreads();
#pragma unroll
  for (int j = 0; j < 4; ++j)
    O[(size_t)(c0 + ty + 8 * j) * DD + r0 + tx] = f2bf(t[tx][ty + 8 * j]);
}

// ---------------------------------------------------------------------------
// Per-batch mask scan -> inverse compaction map rix[b][ct] = t, and cnt[b].
__global__ __launch_bounds__(256) void mask_scan(
    const int* __restrict__ mask, int* __restrict__ rix, int* __restrict__ cnt) {
  __shared__ int part[256];
  const int b = blockIdx.x;
  const int tid = threadIdx.x;
  const int* mp = mask + b * TT;
  for (int i = tid; i < TT; i += 256) rix[b * TT + i] = 0;
  int loc[8], s = 0;
#pragma unroll
  for (int j = 0; j < 8; ++j) {
    loc[j] = mp[tid * 8 + j] ? 1 : 0;
    s += loc[j];
  }
  part[tid] = s;
  __syncthreads();
  for (int off = 1; off < 256; off <<= 1) {
    const int u = (tid >= off) ? part[tid - off] : 0;
    __syncthreads();
    part[tid] += u;
    __syncthreads();
  }
  if (tid == 255) cnt[b] = part[255];
  int run = part[tid] - s;  // exclusive prefix
#pragma unroll
  for (int j = 0; j < 8; ++j) {
    if (loc[j]) rix[b * TT + run] = tid * 8 + j;
    run += loc[j];
  }
}

// ---------------------------------------------------------------------------
// BK=64 swizzled GEMM (round-11 structure, best measured).  EPI 0: fused QKV
// reading f32 x DIRECTLY — A-staging converts f32->bf16 in-register (2x
// float4 load + 4 cvtpk + ds_write_b128 to the swizzled LDS slot), removing
// the standalone cast dispatch.  B (bf16 weights) still via gl_lds.  K/V
// rows rix-gathered -> compacted output.  EPI 1: out-proj (bf16 A, gl_lds).
template <int EPI>
__global__ __launch_bounds__(256) void gemm_v21(
    const void* __restrict__ Ain, const unsigned short* __restrict__ Bw,
    const float* __restrict__ b0, const float* __restrict__ b1,
    const float* __restrict__ b2, const int* __restrict__ rix,
    const int* __restrict__ cnt, unsigned short* __restrict__ O0,
    unsigned short* __restrict__ O1, unsigned short* __restrict__ O2,
    float* __restrict__ Of) {
  __shared__ unsigned short As[128 * 64];
  __shared__ unsigned short Bs[128 * 64];
  const int tid = threadIdx.x;
  const int l = tid & 63, w = tid >> 6;
  const int ln = l & 15, kg = l >> 4;
  const int wr = w >> 1, wc = w & 1;
  const int rb = blockIdx.x * 128, cb = blockIdx.y * 128;
  const int sel = (EPI == 0) ? (blockIdx.y >> 3) : 0;
  const int b_ = rb >> 11;

  const int sr = w * 8 + (l >> 3);
  const int sch = ((l & 7) * 16) ^ (((l >> 3) & 7) << 4);

  // A sources.  EPI 0: f32 rows of x (linear, coalesced); EPI 1: bf16 rows
  // with pre-swizzled source (gl_lds path).
  const float* Af[4];
  const char* Ag[4];
  if constexpr (EPI == 0) {
    const float* X = (const float*)Ain;
    if (sel > 0) {
      const int rbl = rb & 2047;
      if (rbl >= cnt[b_]) return;
      const int* rixb = rix + (b_ << 11);
#pragma unroll
      for (int j = 0; j < 4; ++j) {
        const int r = rixb[rbl + j * 32 + sr];
        Af[j] = X + (size_t)((b_ << 11) + r) * 1024 + (l & 7) * 8;
      }
    } else {
#pragma unroll
      for (int j = 0; j < 4; ++j)
        Af[j] = X + (size_t)(rb + j * 32 + sr) * 1024 + (l & 7) * 8;
    }
  } else {
#pragma unroll
    for (int j = 0; j < 4; ++j)
      Ag[j] = (const char*)Ain + ((size_t)(rb + j * 32 + sr) * 2048) + sch;
  }
  const char* Bg[4];
#pragma unroll
  for (int j = 0; j < 4; ++j)
    Bg[j] = (const char*)Bw + ((size_t)(cb + j * 32 + sr) * 2048) + sch;

  // LDS write slot for the reg-staged A path (row = j*32+sr; row&7 == sr&7,
  // so the swizzled chunk equals sch).
  char* Ald = (char*)As + w * 1024 + (l >> 3) * 128 + sch;

  f32x4 acc[4][4];
#pragma unroll
  for (int i = 0; i < 4; ++i)
#pragma unroll
    for (int j = 0; j < 4; ++j)
#pragma unroll
      for (int r = 0; r < 4; ++r) acc[i][j][r] = 0.f;

  for (int t = 0; t < 16; ++t) {
    const int kb = t * 128;   // bf16 bytes
    const int ke = t * 64;    // elements (f32 index step)
    __syncthreads();
    // B first: DMA overlaps the A f32 load latency
#pragma unroll
    for (int j = 0; j < 4; ++j)
      gl_lds16(Bg[j] + kb, (char*)Bs + j * 4096 + w * 1024);
    if constexpr (EPI == 0) {
#pragma unroll
      for (int j = 0; j < 4; ++j) {
        const float4* s4 = reinterpret_cast<const float4*>(Af[j] + ke);
        const float4 a0 = s4[0], a1 = s4[1];
        uint4 pk;
        pk.x = cvtpk(a0.x, a0.y);
        pk.y = cvtpk(a0.z, a0.w);
        pk.z = cvtpk(a1.x, a1.y);
        pk.w = cvtpk(a1.z, a1.w);
        *reinterpret_cast<uint4*>(Ald + j * 4096) = pk;
      }
    } else {
#pragma unroll
      for (int j = 0; j < 4; ++j)
        gl_lds16(Ag[j] + kb, (char*)As + j * 4096 + w * 1024);
    }
    __syncthreads();
#pragma unroll
    for (int ks = 0; ks < 2; ++ks) {
      bf16x8 af[4], bfv[4];
#pragma unroll
      for (int mi = 0; mi < 4; ++mi) {
        const int row = wr * 64 + mi * 16 + ln;
        af[mi] = *reinterpret_cast<const bf16x8*>(
            (const char*)As + row * 128 + SWZ(row, ks * 64 + kg * 16));
      }
#pragma unroll
      for (int ni = 0; ni < 4; ++ni) {
        const int row = wc * 64 + ni * 16 + ln;
        bfv[ni] = *reinterpret_cast<const bf16x8*>(
            (const char*)Bs + row * 128 + SWZ(row, ks * 64 + kg * 16));
      }
#pragma unroll
      for (int mi = 0; mi < 4; ++mi)
#pragma unroll
        for (int ni = 0; ni < 4; ++ni)
          acc[mi][ni] = __builtin_amdgcn_mfma_f32_16x16x32_bf16(
              af[mi], bfv[ni], acc[mi][ni], 0, 0, 0);
    }
  }

  if constexpr (EPI == 0) {
    const float* bias = sel == 0 ? b0 : (sel == 1 ? b1 : b2);
    const float scale = sel == 0 ? QSCALE : 1.0f;
#pragma unroll
    for (int ni = 0; ni < 4; ++ni) {
      const int c3 = cb + wc * 64 + ni * 16 + ln;
      const int c = c3 & 1023, h = (c3 >> 6) & 15, dk = c3 & 63;
      const float bsv = bias[c];
      const int bh = b_ * HH + h;
#pragma unroll
      for (int mi = 0; mi < 4; ++mi) {
#pragma unroll
        for (int r = 0; r < 4; ++r) {
          const int rl = (rb & 2047) + wr * 64 + mi * 16 + kg * 4 + r;
          const unsigned short v = f2bf((acc[mi][ni][r] + bsv) * scale);
          if (sel == 0) {
            O0[(size_t)(bh * 16 + (rl >> 7)) * 8192 + (dk >> 3) * 1024 +
               (rl & 127) * 8 + (dk & 7)] = v;
          } else if (sel == 1) {
            O1[(size_t)(bh * 32 + (rl >> 6)) * 4096 + (dk >> 3) * 512 +
               ((rl >> 5) & 1) * 256 + (rl & 31) * 8 + (dk & 7)] = v;
          } else {
            O2[(size_t)(bh * 32 + (rl >> 6)) * 4096 + ((rl >> 3) & 7) * 512 +
               (dk >> 5) * 256 + (dk & 31) * 8 + (rl & 7)] = v;
          }
        }
      }
    }
  } else {
#pragma unroll
    for (int ni = 0; ni < 4; ++ni) {
      const int cl = cb + wc * 64 + ni * 16 + ln;
      const float bsv = b0[cl];
#pragma unroll
      for (int mi = 0; mi < 4; ++mi)
#pragma unroll
        for (int r = 0; r < 4; ++r) {
          const int rl = rb + wr * 64 + mi * 16 + kg * 4 + r;
          Of[(size_t)rl * DD + cl] = acc[mi][ni][r] + bsv;
        }
    }
  }
}

// ---------------------------------------------------------------------------
// attn v10 tile body (round-10 verified).  TAIL: zero P at pos >= n.
template <bool TAIL>
__device__ __forceinline__ void attn_tile10(
    int kt, int n, const char* __restrict__ KU, const char* __restrict__ VU,
    int foff, int hi, const bf16x8 (&qf)[4], f32x16& oc0, f32x16& oc1,
    float& l_) {
  const int ktoff = kt << 13;

  f32x16 sc0, sc1;
#pragma unroll
  for (int i = 0; i < 16; ++i) { sc0[i] = 0.f; sc1[i] = 0.f; }
  __builtin_amdgcn_s_setprio(1);
#pragma unroll
  for (int s = 0; s < 4; ++s) {
    const bf16x8 kf0 =
        *reinterpret_cast<const bf16x8*>(KU + ktoff + foff + s * 2048);
    const bf16x8 kf1 =
        *reinterpret_cast<const bf16x8*>(KU + ktoff + foff + s * 2048 + 512);
    sc0 = __builtin_amdgcn_mfma_f32_32x32x16_bf16(kf0, qf[s], sc0, 0, 0, 0);
    sc1 = __builtin_amdgcn_mfma_f32_32x32x16_bf16(kf1, qf[s], sc1, 0, 0, 0);
  }
  __builtin_amdgcn_s_setprio(0);

  bf16x8 vf[8];
#pragma unroll
  for (int s = 0; s < 4; ++s) {
    vf[2 * s] = *reinterpret_cast<const bf16x8*>(VU + ktoff + foff + s * 2048);
    vf[2 * s + 1] =
        *reinterpret_cast<const bf16x8*>(VU + ktoff + foff + s * 2048 + 512);
  }

#pragma unroll
  for (int i = 0; i < 16; ++i) sc0[i] = __builtin_exp2f(sc0[i]);
#pragma unroll
  for (int i = 0; i < 16; ++i) sc1[i] = __builtin_exp2f(sc1[i]);

  if (TAIL) {
    const int kvb = (kt << 6) + 4 * hi;
#pragma unroll
    for (int i = 0; i < 16; ++i) {
      const int kv0 = kvb + (i & 3) + 8 * (i >> 2);
      sc0[i] = (kv0 < n) ? sc0[i] : 0.f;
      sc1[i] = (kv0 + 32 < n) ? sc1[i] : 0.f;
    }
  }

  {
    const float ra = ((sc0[0] + sc0[1]) + (sc0[2] + sc0[3])) +
                     ((sc0[4] + sc0[5]) + (sc0[6] + sc0[7]));
    const float rb2 = ((sc0[8] + sc0[9]) + (sc0[10] + sc0[11])) +
                      ((sc0[12] + sc0[13]) + (sc0[14] + sc0[15]));
    const float rc = ((sc1[0] + sc1[1]) + (sc1[2] + sc1[3])) +
                     ((sc1[4] + sc1[5]) + (sc1[6] + sc1[7]));
    const float rd = ((sc1[8] + sc1[9]) + (sc1[10] + sc1[11])) +
                     ((sc1[12] + sc1[13]) + (sc1[14] + sc1[15]));
    l_ += (ra + rb2) + (rc + rd);
  }

  bf16x8 pf[4];
#pragma unroll
  for (int s = 0; s < 4; ++s) {
    const int u = s & 1;
    float p0, p1, p2, p3, p4, p5, p6, p7;
    if ((s >> 1) == 0) {
      p0 = sc0[8 * u + 0]; p1 = sc0[8 * u + 1]; p2 = sc0[8 * u + 2];
      p3 = sc0[8 * u + 3]; p4 = sc0[8 * u + 4]; p5 = sc0[8 * u + 5];
      p6 = sc0[8 * u + 6]; p7 = sc0[8 * u + 7];
    } else {
      p0 = sc1[8 * u + 0]; p1 = sc1[8 * u + 1]; p2 = sc1[8 * u + 2];
      p3 = sc1[8 * u + 3]; p4 = sc1[8 * u + 4]; p5 = sc1[8 * u + 5];
      p6 = sc1[8 * u + 6]; p7 = sc1[8 * u + 7];
    }
    const unsigned int wa0 = cvtpk(p0, p1), wa1 = cvtpk(p2, p3);
    const unsigned int wb0 = cvtpk(p4, p5), wb1 = cvtpk(p6, p7);
    const uint2v r0 = __builtin_amdgcn_permlane32_swap(wa0, wb0, false, false);
    const uint2v r1 = __builtin_amdgcn_permlane32_swap(wa1, wb1, false, false);
    union { unsigned int u4[4]; bf16x8 v; } pw;
    pw.u4[0] = r0.x;
    pw.u4[1] = r1.x;
    pw.u4[2] = r0.y;
    pw.u4[3] = r1.y;
    pf[s] = pw.v;
  }

  __builtin_amdgcn_s_setprio(1);
#pragma unroll
  for (int s = 0; s < 4; ++s) {
    oc0 = __builtin_amdgcn_mfma_f32_32x32x16_bf16(vf[2 * s], pf[s], oc0, 0, 0, 0);
    oc1 = __builtin_amdgcn_mfma_f32_32x32x16_bf16(vf[2 * s + 1], pf[s], oc1, 0, 0, 0);
  }
  __builtin_amdgcn_s_setprio(0);
}

// ---------------------------------------------------------------------------
// Flash attention v10 (round-10/11 verified): mask-compacted KV, barrier-free
// register-direct K/V, lane-local l, permlane P-build.  84 VGPR — any
// register-prefetch variant crosses the 128-VGPR cliff and regresses (r8,r17).
__global__ __launch_bounds__(256) void attn_v10(
    const unsigned short* __restrict__ Qt, const unsigned short* __restrict__ Kt,
    const unsigned short* __restrict__ Vt, const int* __restrict__ cnt,
    unsigned short* __restrict__ Ab) {
  const int id = blockIdx.x + 16 * blockIdx.y;
  const int bh = id & 63, qt = id >> 6;
  const int b = bh >> 4, h = bh & 15;

  __shared__ __align__(16) char lds[16384];  // O transpose buffer

  const int tid = threadIdx.x;
  const int l = tid & 63, w = tid >> 6;
  const int ln = l & 31, hi = l >> 5;

  const char* Qtile = (const char*)Qt + (size_t)(bh * 16 + qt) * 16384;
  const char* KU = (const char*)Kt + ((size_t)bh << 18);
  const char* VU = (const char*)Vt + ((size_t)bh << 18);
  const int n = cnt[b];
  const int ntile = (n > 0) ? ((n + 63) >> 6) : 1;

  const int qrow = w * 32 + ln;
  bf16x8 qf[4];
#pragma unroll
  for (int s = 0; s < 4; ++s)
    qf[s] = *reinterpret_cast<const bf16x8*>(
        Qtile + (size_t)(s * 2 + hi) * 2048 + qrow * 16);

  const int foff = hi * 1024 + ln * 16;

  f32x16 oc0, oc1;
#pragma unroll
  for (int i = 0; i < 16; ++i) { oc0[i] = 0.f; oc1[i] = 0.f; }
  float l_ = 0.f;

  for (int kt = 0; kt + 1 < ntile; ++kt)
    attn_tile10<false>(kt, n, KU, VU, foff, hi, qf, oc0, oc1, l_);
  attn_tile10<true>(ntile - 1, n, KU, VU, foff, hi, qf, oc0, oc1, l_);

  float ls = l_ + __shfl_xor(l_, 32);
  const float inv = 1.0f / ls;
#pragma unroll
  for (int i = 0; i < 16; ++i) { oc0[i] *= inv; oc1[i] *= inv; }
#pragma unroll
  for (int g = 0; g < 4; ++g) {
    const int d0a = 8 * g + 4 * hi;
    uint2 wv;
    wv.x = cvtpk(oc0[4 * g + 0], oc0[4 * g + 1]);
    wv.y = cvtpk(oc0[4 * g + 2], oc0[4 * g + 3]);
    *reinterpret_cast<uint2*>(lds + qrow * 128 + SWZ(qrow, d0a * 2)) = wv;
    uint2 wv1;
    wv1.x = cvtpk(oc1[4 * g + 0], oc1[4 * g + 1]);
    wv1.y = cvtpk(oc1[4 * g + 2], oc1[4 * g + 3]);
    *reinterpret_cast<uint2*>(lds + qrow * 128 + SWZ(qrow, 64 + d0a * 2)) = wv1;
  }
  __syncthreads();
  {
    const int row2 = tid >> 1, halfc = tid & 1;
    char* gout = (char*)Ab + ((size_t)(b * TT + qt * 128 + row2)) * 2048 +
                 h * 128 + halfc * 64;
#pragma unroll
    for (int u2 = 0; u2 < 4; ++u2) {
      const uint4 d4 = *reinterpret_cast<const uint4*>(
          lds + row2 * 128 + SWZ(row2, halfc * 64 + u2 * 16));
      *reinterpret_cast<uint4*>(gout + u2 * 16) = d4;
    }
  }
}

// ---------------------------------------------------------------------------
extern "C" void kernel_launch(void* const* d_in, const int* in_sizes, int n_in,
                              void* d_out, int out_size, void* d_ws,
                              size_t ws_size, hipStream_t stream) {
  const float* x = (const float*)d_in[0];
  const int* attn_mask = (const int*)d_in[1];
  const float* wq = (const float*)d_in[2];
  const float* bq = (const float*)d_in[3];
  const float* wk = (const float*)d_in[4];
  const float* bk = (const float*)d_in[5];
  const float* wv = (const float*)d_in[6];
  const float* bv = (const float*)d_in[7];
  const float* wo = (const float*)d_in[8];
  const float* bo = (const float*)d_in[9];
  float* out = (float*)d_out;

  unsigned short* WT = (unsigned short*)d_ws;          // 4*DD*DD (q,k,v,o ^T)
  unsigned short* Qt = WT + (size_t)4 * DD * DD;       // tiled Q (pre-scaled)
  unsigned short* Kt = Qt + (size_t)NN * DD;           // tiled K (compacted)
  unsigned short* Vt = Kt + (size_t)NN * DD;           // tiled V^T (compacted)
  unsigned short* Ab = Vt + (size_t)NN * DD;           // (B,T,D) bf16
  int* rix = (int*)(Ab + (size_t)NN * DD);             // BB*TT inverse map
  int* cnt = rix + (size_t)BB * TT;                    // BB counts

  wtrans<<<dim3(DD / 32, DD / 32, 4), 256, 0, stream>>>(wq, wk, wv, wo, WT);
  mask_scan<<<BB, 256, 0, stream>>>(attn_mask, rix, cnt);

  gemm_v21<0><<<dim3(NN / 128, 24), 256, 0, stream>>>(
      x, WT, bq, bk, bv, rix, cnt, Qt, Kt, Vt, nullptr);
  attn_v10<<<dim3(TT / 128, BB * HH), 256, 0, stream>>>(Qt, Kt, Vt, cnt, Ab);
  gemm_v21<1><<<dim3(NN / 128, 8), 256, 0, stream>>>(
      Ab, WT + (size_t)3 * DD * DD, bo, nullptr, nullptr, nullptr, nullptr,
      nullptr, nullptr, nullptr, out);
}

// Round 22
// 171.507 us; speedup vs baseline: 1.2594x; 1.2594x over previous
//
#include <hip/hip_runtime.h>
#include <math.h>

#define TT 2048
#define DD 1024
#define HH 16
#define DKK 64
#define BB 4
#define NN 8192  // BB*TT

typedef __bf16 bf16x8 __attribute__((ext_vector_type(8)));
typedef float f32x4 __attribute__((ext_vector_type(4)));
typedef float f32x16 __attribute__((ext_vector_type(16)));
typedef unsigned int uint2v __attribute__((ext_vector_type(2)));

#define QSCALE 0.18033688011112043f   // 0.125 * log2(e)

// round-to-nearest-even f32 -> bf16 bits
__device__ __forceinline__ unsigned short f2bf(float f) {
  unsigned int u = __builtin_bit_cast(unsigned int, f);
  u += 0x7fffu + ((u >> 16) & 1u);
  return (unsigned short)(u >> 16);
}

// v_cvt_pk_bf16_f32: dst.lo16 = bf16(lo), dst.hi16 = bf16(hi)
__device__ __forceinline__ unsigned int cvtpk(float lo, float hi) {
  unsigned int r;
  asm("v_cvt_pk_bf16_f32 %0, %1, %2" : "=v"(r) : "v"(lo), "v"(hi));
  return r;
}

__device__ __forceinline__ void gl_lds16(const void* g, void* s) {
  __builtin_amdgcn_global_load_lds(
      (const __attribute__((address_space(1))) void*)g,
      (__attribute__((address_space(3))) void*)s, 16, 0, 0);
}

// XOR swizzle within a 128B row (both-sides pattern, verified rounds 2-20)
#define SWZ(r, byte) ((byte) ^ (((r) & 7) << 4))

// ---------------------------------------------------------------------------
__global__ __launch_bounds__(256) void cast_f32_bf16(
    const float* __restrict__ in, unsigned short* __restrict__ out, int n4) {
  int i = blockIdx.x * blockDim.x + threadIdx.x;
  if (i < n4) {
    float4 v = reinterpret_cast<const float4*>(in)[i];
    ushort4 o;
    o.x = f2bf(v.x); o.y = f2bf(v.y); o.z = f2bf(v.z); o.w = f2bf(v.w);
    reinterpret_cast<ushort4*>(out)[i] = o;
  }
}

// transpose + cast 4 weights (DDxDD f32 row-major [k][n]) -> WT bf16 [n][k]
__global__ __launch_bounds__(256) void wtrans(
    const float* __restrict__ W0, const float* __restrict__ W1,
    const float* __restrict__ W2, const float* __restrict__ W3,
    unsigned short* __restrict__ WT) {
  __shared__ float t[32][33];
  const float* W = (blockIdx.z == 0) ? W0
                   : (blockIdx.z == 1) ? W1
                   : (blockIdx.z == 2) ? W2 : W3;
  unsigned short* O = WT + (size_t)blockIdx.z * DD * DD;
  const int tx = threadIdx.x & 31, ty = threadIdx.x >> 5;
  const int r0 = blockIdx.y * 32, c0 = blockIdx.x * 32;
#pragma unroll
  for (int j = 0; j < 4; ++j)
    t[ty + 8 * j][tx] = W[(size_t)(r0 + ty + 8 * j) * DD + c0 + tx];
  __syncthreads();
#pragma unroll
  for (int j = 0; j < 4; ++j)
    O[(size_t)(c0 + ty + 8 * j) * DD + r0 + tx] = f2bf(t[tx][ty + 8 * j]);
}

// ---------------------------------------------------------------------------
// Per-batch mask scan -> inverse compaction map rix[b][ct] = t, and cnt[b].
__global__ __launch_bounds__(256) void mask_scan(
    const int* __restrict__ mask, int* __restrict__ rix, int* __restrict__ cnt) {
  __shared__ int part[256];
  const int b = blockIdx.x;
  const int tid = threadIdx.x;
  const int* mp = mask + b * TT;
  for (int i = tid; i < TT; i += 256) rix[b * TT + i] = 0;
  int loc[8], s = 0;
#pragma unroll
  for (int j = 0; j < 8; ++j) {
    loc[j] = mp[tid * 8 + j] ? 1 : 0;
    s += loc[j];
  }
  part[tid] = s;
  __syncthreads();
  for (int off = 1; off < 256; off <<= 1) {
    const int u = (tid >= off) ? part[tid - off] : 0;
    __syncthreads();
    part[tid] += u;
    __syncthreads();
  }
  if (tid == 255) cnt[b] = part[255];
  int run = part[tid] - s;  // exclusive prefix
#pragma unroll
  for (int j = 0; j < 8; ++j) {
    if (loc[j]) rix[b * TT + run] = tid * 8 + j;
    run += loc[j];
  }
}

// ---------------------------------------------------------------------------
// BK=64 swizzled GEMM (round-11, best measured of 10 structural variants):
// 128B LDS rows, both-sides XOR swizzle, 16 K-steps, single-buffered,
// 2 barriers/step.  EPI 0: fused QKV; Q rows direct, K/V rows GATHERED
// through rix so the output is compacted contiguously (blocks past cnt
// exit).  EPI 1: out-proj, f32 row-major.
template <int EPI>
__global__ __launch_bounds__(256) void gemm_v11(
    const unsigned short* __restrict__ A, const unsigned short* __restrict__ Bw,
    const float* __restrict__ b0, const float* __restrict__ b1,
    const float* __restrict__ b2, const int* __restrict__ rix,
    const int* __restrict__ cnt, unsigned short* __restrict__ O0,
    unsigned short* __restrict__ O1, unsigned short* __restrict__ O2,
    float* __restrict__ Of) {
  __shared__ unsigned short As[128 * 64];
  __shared__ unsigned short Bs[128 * 64];
  const int tid = threadIdx.x;
  const int l = tid & 63, w = tid >> 6;
  const int ln = l & 15, kg = l >> 4;
  const int wr = w >> 1, wc = w & 1;
  const int rb = blockIdx.x * 128, cb = blockIdx.y * 128;
  const int sel = (EPI == 0) ? (blockIdx.y >> 3) : 0;
  const int b_ = rb >> 11;

  const int sr = w * 8 + (l >> 3);
  const int sch = ((l & 7) * 16) ^ (((l >> 3) & 7) << 4);

  const char* Ag[4];
  if (EPI == 0 && sel > 0) {
    const int rbl = rb & 2047;
    if (rbl >= cnt[b_]) return;
    const int* rixb = rix + (b_ << 11);
#pragma unroll
    for (int j = 0; j < 4; ++j) {
      const int r = rixb[rbl + j * 32 + sr];
      Ag[j] = (const char*)A + ((size_t)((b_ << 11) + r) * 2048) + sch;
    }
  } else {
#pragma unroll
    for (int j = 0; j < 4; ++j)
      Ag[j] = (const char*)A + ((size_t)(rb + j * 32 + sr) * 2048) + sch;
  }
  const char* Bg[4];
#pragma unroll
  for (int j = 0; j < 4; ++j)
    Bg[j] = (const char*)Bw + ((size_t)(cb + j * 32 + sr) * 2048) + sch;

  f32x4 acc[4][4];
#pragma unroll
  for (int i = 0; i < 4; ++i)
#pragma unroll
    for (int j = 0; j < 4; ++j)
#pragma unroll
      for (int r = 0; r < 4; ++r) acc[i][j][r] = 0.f;

  for (int kb = 0; kb < 2048; kb += 128) {  // 16 K-steps of 64 bf16
    __syncthreads();
#pragma unroll
    for (int j = 0; j < 4; ++j) {
      gl_lds16(Ag[j] + kb, (char*)As + j * 4096 + w * 1024);
      gl_lds16(Bg[j] + kb, (char*)Bs + j * 4096 + w * 1024);
    }
    __syncthreads();
#pragma unroll
    for (int ks = 0; ks < 2; ++ks) {
      bf16x8 af[4], bfv[4];
#pragma unroll
      for (int mi = 0; mi < 4; ++mi) {
        const int row = wr * 64 + mi * 16 + ln;
        af[mi] = *reinterpret_cast<const bf16x8*>(
            (const char*)As + row * 128 + SWZ(row, ks * 64 + kg * 16));
      }
#pragma unroll
      for (int ni = 0; ni < 4; ++ni) {
        const int row = wc * 64 + ni * 16 + ln;
        bfv[ni] = *reinterpret_cast<const bf16x8*>(
            (const char*)Bs + row * 128 + SWZ(row, ks * 64 + kg * 16));
      }
#pragma unroll
      for (int mi = 0; mi < 4; ++mi)
#pragma unroll
        for (int ni = 0; ni < 4; ++ni)
          acc[mi][ni] = __builtin_amdgcn_mfma_f32_16x16x32_bf16(
              af[mi], bfv[ni], acc[mi][ni], 0, 0, 0);
    }
  }

  if constexpr (EPI == 0) {
    const float* bias = sel == 0 ? b0 : (sel == 1 ? b1 : b2);
    const float scale = sel == 0 ? QSCALE : 1.0f;
#pragma unroll
    for (int ni = 0; ni < 4; ++ni) {
      const int c3 = cb + wc * 64 + ni * 16 + ln;
      const int c = c3 & 1023, h = (c3 >> 6) & 15, dk = c3 & 63;
      const float bsv = bias[c];
      const int bh = b_ * HH + h;
#pragma unroll
      for (int mi = 0; mi < 4; ++mi) {
#pragma unroll
        for (int r = 0; r < 4; ++r) {
          const int rl = (rb & 2047) + wr * 64 + mi * 16 + kg * 4 + r;
          const unsigned short v = f2bf((acc[mi][ni][r] + bsv) * scale);
          if (sel == 0) {
            O0[(size_t)(bh * 16 + (rl >> 7)) * 8192 + (dk >> 3) * 1024 +
               (rl & 127) * 8 + (dk & 7)] = v;
          } else if (sel == 1) {
            O1[(size_t)(bh * 32 + (rl >> 6)) * 4096 + (dk >> 3) * 512 +
               ((rl >> 5) & 1) * 256 + (rl & 31) * 8 + (dk & 7)] = v;
          } else {
            O2[(size_t)(bh * 32 + (rl >> 6)) * 4096 + ((rl >> 3) & 7) * 512 +
               (dk >> 5) * 256 + (dk & 31) * 8 + (rl & 7)] = v;
          }
        }
      }
    }
  } else {
#pragma unroll
    for (int ni = 0; ni < 4; ++ni) {
      const int cl = cb + wc * 64 + ni * 16 + ln;
      const float bsv = b0[cl];
#pragma unroll
      for (int mi = 0; mi < 4; ++mi)
#pragma unroll
        for (int r = 0; r < 4; ++r) {
          const int rl = rb + wr * 64 + mi * 16 + kg * 4 + r;
          Of[(size_t)rl * DD + cl] = acc[mi][ni][r] + bsv;
        }
    }
  }
}

// ---------------------------------------------------------------------------
// attn v10 tile body (round-10 verified).  TAIL: zero P at pos >= n.
template <bool TAIL>
__device__ __forceinline__ void attn_tile10(
    int kt, int n, const char* __restrict__ KU, const char* __restrict__ VU,
    int foff, int hi, const bf16x8 (&qf)[4], f32x16& oc0, f32x16& oc1,
    float& l_) {
  const int ktoff = kt << 13;

  f32x16 sc0, sc1;
#pragma unroll
  for (int i = 0; i < 16; ++i) { sc0[i] = 0.f; sc1[i] = 0.f; }
  __builtin_amdgcn_s_setprio(1);
#pragma unroll
  for (int s = 0; s < 4; ++s) {
    const bf16x8 kf0 =
        *reinterpret_cast<const bf16x8*>(KU + ktoff + foff + s * 2048);
    const bf16x8 kf1 =
        *reinterpret_cast<const bf16x8*>(KU + ktoff + foff + s * 2048 + 512);
    sc0 = __builtin_amdgcn_mfma_f32_32x32x16_bf16(kf0, qf[s], sc0, 0, 0, 0);
    sc1 = __builtin_amdgcn_mfma_f32_32x32x16_bf16(kf1, qf[s], sc1, 0, 0, 0);
  }
  __builtin_amdgcn_s_setprio(0);

  bf16x8 vf[8];
#pragma unroll
  for (int s = 0; s < 4; ++s) {
    vf[2 * s] = *reinterpret_cast<const bf16x8*>(VU + ktoff + foff + s * 2048);
    vf[2 * s + 1] =
        *reinterpret_cast<const bf16x8*>(VU + ktoff + foff + s * 2048 + 512);
  }

#pragma unroll
  for (int i = 0; i < 16; ++i) sc0[i] = __builtin_exp2f(sc0[i]);
#pragma unroll
  for (int i = 0; i < 16; ++i) sc1[i] = __builtin_exp2f(sc1[i]);

  if (TAIL) {
    const int kvb = (kt << 6) + 4 * hi;
#pragma unroll
    for (int i = 0; i < 16; ++i) {
      const int kv0 = kvb + (i & 3) + 8 * (i >> 2);
      sc0[i] = (kv0 < n) ? sc0[i] : 0.f;
      sc1[i] = (kv0 + 32 < n) ? sc1[i] : 0.f;
    }
  }

  {
    const float ra = ((sc0[0] + sc0[1]) + (sc0[2] + sc0[3])) +
                     ((sc0[4] + sc0[5]) + (sc0[6] + sc0[7]));
    const float rb2 = ((sc0[8] + sc0[9]) + (sc0[10] + sc0[11])) +
                      ((sc0[12] + sc0[13]) + (sc0[14] + sc0[15]));
    const float rc = ((sc1[0] + sc1[1]) + (sc1[2] + sc1[3])) +
                     ((sc1[4] + sc1[5]) + (sc1[6] + sc1[7]));
    const float rd = ((sc1[8] + sc1[9]) + (sc1[10] + sc1[11])) +
                     ((sc1[12] + sc1[13]) + (sc1[14] + sc1[15]));
    l_ += (ra + rb2) + (rc + rd);
  }

  bf16x8 pf[4];
#pragma unroll
  for (int s = 0; s < 4; ++s) {
    const int u = s & 1;
    float p0, p1, p2, p3, p4, p5, p6, p7;
    if ((s >> 1) == 0) {
      p0 = sc0[8 * u + 0]; p1 = sc0[8 * u + 1]; p2 = sc0[8 * u + 2];
      p3 = sc0[8 * u + 3]; p4 = sc0[8 * u + 4]; p5 = sc0[8 * u + 5];
      p6 = sc0[8 * u + 6]; p7 = sc0[8 * u + 7];
    } else {
      p0 = sc1[8 * u + 0]; p1 = sc1[8 * u + 1]; p2 = sc1[8 * u + 2];
      p3 = sc1[8 * u + 3]; p4 = sc1[8 * u + 4]; p5 = sc1[8 * u + 5];
      p6 = sc1[8 * u + 6]; p7 = sc1[8 * u + 7];
    }
    const unsigned int wa0 = cvtpk(p0, p1), wa1 = cvtpk(p2, p3);
    const unsigned int wb0 = cvtpk(p4, p5), wb1 = cvtpk(p6, p7);
    const uint2v r0 = __builtin_amdgcn_permlane32_swap(wa0, wb0, false, false);
    const uint2v r1 = __builtin_amdgcn_permlane32_swap(wa1, wb1, false, false);
    union { unsigned int u4[4]; bf16x8 v; } pw;
    pw.u4[0] = r0.x;
    pw.u4[1] = r1.x;
    pw.u4[2] = r0.y;
    pw.u4[3] = r1.y;
    pf[s] = pw.v;
  }

  __builtin_amdgcn_s_setprio(1);
#pragma unroll
  for (int s = 0; s < 4; ++s) {
    oc0 = __builtin_amdgcn_mfma_f32_32x32x16_bf16(vf[2 * s], pf[s], oc0, 0, 0, 0);
    oc1 = __builtin_amdgcn_mfma_f32_32x32x16_bf16(vf[2 * s + 1], pf[s], oc1, 0, 0, 0);
  }
  __builtin_amdgcn_s_setprio(0);
}

// ---------------------------------------------------------------------------
// Flash attention v10 (round-10/11 verified): mask-compacted KV, barrier-free
// register-direct K/V, lane-local l, permlane P-build.  84 VGPR — any
// register-prefetch variant crosses the 128-VGPR cliff and regresses (r8,r17).
__global__ __launch_bounds__(256) void attn_v10(
    const unsigned short* __restrict__ Qt, const unsigned short* __restrict__ Kt,
    const unsigned short* __restrict__ Vt, const int* __restrict__ cnt,
    unsigned short* __restrict__ Ab) {
  const int id = blockIdx.x + 16 * blockIdx.y;
  const int bh = id & 63, qt = id >> 6;
  const int b = bh >> 4, h = bh & 15;

  __shared__ __align__(16) char lds[16384];  // O transpose buffer

  const int tid = threadIdx.x;
  const int l = tid & 63, w = tid >> 6;
  const int ln = l & 31, hi = l >> 5;

  const char* Qtile = (const char*)Qt + (size_t)(bh * 16 + qt) * 16384;
  const char* KU = (const char*)Kt + ((size_t)bh << 18);
  const char* VU = (const char*)Vt + ((size_t)bh << 18);
  const int n = cnt[b];
  const int ntile = (n > 0) ? ((n + 63) >> 6) : 1;

  const int qrow = w * 32 + ln;
  bf16x8 qf[4];
#pragma unroll
  for (int s = 0; s < 4; ++s)
    qf[s] = *reinterpret_cast<const bf16x8*>(
        Qtile + (size_t)(s * 2 + hi) * 2048 + qrow * 16);

  const int foff = hi * 1024 + ln * 16;

  f32x16 oc0, oc1;
#pragma unroll
  for (int i = 0; i < 16; ++i) { oc0[i] = 0.f; oc1[i] = 0.f; }
  float l_ = 0.f;

  for (int kt = 0; kt + 1 < ntile; ++kt)
    attn_tile10<false>(kt, n, KU, VU, foff, hi, qf, oc0, oc1, l_);
  attn_tile10<true>(ntile - 1, n, KU, VU, foff, hi, qf, oc0, oc1, l_);

  float ls = l_ + __shfl_xor(l_, 32);
  const float inv = 1.0f / ls;
#pragma unroll
  for (int i = 0; i < 16; ++i) { oc0[i] *= inv; oc1[i] *= inv; }
#pragma unroll
  for (int g = 0; g < 4; ++g) {
    const int d0a = 8 * g + 4 * hi;
    uint2 wv;
    wv.x = cvtpk(oc0[4 * g + 0], oc0[4 * g + 1]);
    wv.y = cvtpk(oc0[4 * g + 2], oc0[4 * g + 3]);
    *reinterpret_cast<uint2*>(lds + qrow * 128 + SWZ(qrow, d0a * 2)) = wv;
    uint2 wv1;
    wv1.x = cvtpk(oc1[4 * g + 0], oc1[4 * g + 1]);
    wv1.y = cvtpk(oc1[4 * g + 2], oc1[4 * g + 3]);
    *reinterpret_cast<uint2*>(lds + qrow * 128 + SWZ(qrow, 64 + d0a * 2)) = wv1;
  }
  __syncthreads();
  {
    const int row2 = tid >> 1, halfc = tid & 1;
    char* gout = (char*)Ab + ((size_t)(b * TT + qt * 128 + row2)) * 2048 +
                 h * 128 + halfc * 64;
#pragma unroll
    for (int u2 = 0; u2 < 4; ++u2) {
      const uint4 d4 = *reinterpret_cast<const uint4*>(
          lds + row2 * 128 + SWZ(row2, halfc * 64 + u2 * 16));
      *reinterpret_cast<uint4*>(gout + u2 * 16) = d4;
    }
  }
}

// ---------------------------------------------------------------------------
extern "C" void kernel_launch(void* const* d_in, const int* in_sizes, int n_in,
                              void* d_out, int out_size, void* d_ws,
                              size_t ws_size, hipStream_t stream) {
  const float* x = (const float*)d_in[0];
  const int* attn_mask = (const int*)d_in[1];
  const float* wq = (const float*)d_in[2];
  const float* bq = (const float*)d_in[3];
  const float* wk = (const float*)d_in[4];
  const float* bk = (const float*)d_in[5];
  const float* wv = (const float*)d_in[6];
  const float* bv = (const float*)d_in[7];
  const float* wo = (const float*)d_in[8];
  const float* bo = (const float*)d_in[9];
  float* out = (float*)d_out;

  unsigned short* Xb = (unsigned short*)d_ws;          // NN*DD bf16
  unsigned short* WT = Xb + (size_t)NN * DD;           // 4*DD*DD (q,k,v,o ^T)
  unsigned short* Qt = WT + (size_t)4 * DD * DD;       // tiled Q (pre-scaled)
  unsigned short* Kt = Qt + (size_t)NN * DD;           // tiled K (compacted)
  unsigned short* Vt = Kt + (size_t)NN * DD;           // tiled V^T (compacted)
  unsigned short* Ab = Vt + (size_t)NN * DD;           // (B,T,D) bf16
  int* rix = (int*)(Ab + (size_t)NN * DD);             // BB*TT inverse map
  int* cnt = rix + (size_t)BB * TT;                    // BB counts

  cast_f32_bf16<<<(NN * DD / 4 + 255) / 256, 256, 0, stream>>>(
      x, Xb, NN * DD / 4);
  wtrans<<<dim3(DD / 32, DD / 32, 4), 256, 0, stream>>>(wq, wk, wv, wo, WT);
  mask_scan<<<BB, 256, 0, stream>>>(attn_mask, rix, cnt);

  gemm_v11<0><<<dim3(NN / 128, 24), 256, 0, stream>>>(
      Xb, WT, bq, bk, bv, rix, cnt, Qt, Kt, Vt, nullptr);
  attn_v10<<<dim3(TT / 128, BB * HH), 256, 0, stream>>>(Qt, Kt, Vt, cnt, Ab);
  gemm_v11<1><<<dim3(NN / 128, 8), 256, 0, stream>>>(
      Ab, WT + (size_t)3 * DD * DD, bo, nullptr, nullptr, nullptr, nullptr,
      nullptr, nullptr, nullptr, out);
}